// Round 1
// baseline (398.543 us; speedup 1.0000x reference)
//
#include <hip/hip_runtime.h>
#include <math.h>

#define BB 8
#define FF 4096
#define DD 1024
#define HH 8

// ---------------------------------------------------------------------------
// K1: scores[r*H+h] = sum_d |x[r][d]| * W[d][h] + b[h], f64 accumulation.
// One wave per row (grid-stride). Each lane owns 16 fixed d-indices
// (d = (lane+64j)*4+c), W for those indices preloaded into VGPRs once.
// ---------------------------------------------------------------------------
__global__ __launch_bounds__(256) void k_scores(const float* __restrict__ x,
                                                const float* __restrict__ W,
                                                const float* __restrict__ b,
                                                float* __restrict__ scores) {
    const int lane  = threadIdx.x & 63;
    const int gwave = (int)((blockIdx.x * blockDim.x + threadIdx.x) >> 6);
    const int nwave = (int)((gridDim.x * blockDim.x) >> 6);

    // Preload this lane's W rows into registers: 16 d-values x 8 heads.
    float wreg[16][8];
#pragma unroll
    for (int j = 0; j < 4; ++j) {
#pragma unroll
        for (int c = 0; c < 4; ++c) {
            const int d = (lane + 64 * j) * 4 + c;
            const float4* wp = (const float4*)(W + (size_t)d * HH);
            float4 w0 = wp[0];
            float4 w1 = wp[1];
            wreg[j * 4 + c][0] = w0.x; wreg[j * 4 + c][1] = w0.y;
            wreg[j * 4 + c][2] = w0.z; wreg[j * 4 + c][3] = w0.w;
            wreg[j * 4 + c][4] = w1.x; wreg[j * 4 + c][5] = w1.y;
            wreg[j * 4 + c][6] = w1.z; wreg[j * 4 + c][7] = w1.w;
        }
    }

    for (int r = gwave; r < BB * FF; r += nwave) {
        const float4* px = (const float4*)(x + (size_t)r * DD);
        double acc[8] = {0, 0, 0, 0, 0, 0, 0, 0};
#pragma unroll
        for (int j = 0; j < 4; ++j) {
            float4 v = px[lane + 64 * j];
            const float m0 = fabsf(v.x), m1 = fabsf(v.y),
                        m2 = fabsf(v.z), m3 = fabsf(v.w);
#pragma unroll
            for (int h = 0; h < 8; ++h) {
                acc[h] += (double)m0 * (double)wreg[j * 4 + 0][h]
                        + (double)m1 * (double)wreg[j * 4 + 1][h]
                        + (double)m2 * (double)wreg[j * 4 + 2][h]
                        + (double)m3 * (double)wreg[j * 4 + 3][h];
            }
        }
        // wave-wide reduction (64 lanes) per head
#pragma unroll
        for (int h = 0; h < 8; ++h) {
            double v = acc[h];
            for (int off = 32; off > 0; off >>= 1) v += __shfl_down(v, off, 64);
            if (lane == 0)
                scores[(size_t)r * HH + h] = (float)(v + (double)b[h]);
        }
    }
}

// ---------------------------------------------------------------------------
// K2: per (b,h) exact top-k via 8-bit radix select on order-preserving
// uint32 keys; stable lowest-index tie-break (matches lax.top_k).
// One block of 256 threads per (b,h); 64 blocks total.
// ---------------------------------------------------------------------------
__global__ __launch_bounds__(256) void k_topk(const float* __restrict__ scores,
                                              const float* __restrict__ soff,
                                              float* __restrict__ mask_out) {
    const int blk = blockIdx.x;      // b*H + h
    const int b   = blk >> 3;
    const int h   = blk & 7;
    const int tid = threadIdx.x;

    __shared__ unsigned int keys[FF];        // 16 KB
    __shared__ unsigned int hist[256];
    __shared__ unsigned int tcnt[256];
    __shared__ unsigned int sh_digit, sh_remaining;

    // k per head — mirror the reference's float64 path exactly.
    double o  = (double)soff[h];
    double sp = 1.0 / (1.0 + exp(-o)) * 0.3 + 0.15;
    int k = (int)((double)FF * sp);
    if (k < 1) k = 1;

    // Load scores -> order-preserving keys (larger float => larger uint).
    for (int i = 0; i < 16; ++i) {
        const int f = tid * 16 + i;
        const float s = scores[((size_t)b * FF + f) * HH + h];
        const unsigned int u = __float_as_uint(s);
        keys[f] = (u & 0x80000000u) ? ~u : (u | 0x80000000u);
    }
    __syncthreads();

    unsigned int remaining = (unsigned int)k;  // elements still to place
    unsigned int prefix = 0;                   // high bits of k-th largest key
    unsigned int pmask  = 0;                   // which bits are fixed
    for (int pass = 3; pass >= 0; --pass) {
        const int shift = pass * 8;
        hist[tid] = 0;
        __syncthreads();
        for (int i = 0; i < 16; ++i) {
            const unsigned int key = keys[tid * 16 + i];
            if ((key & pmask) == prefix)
                atomicAdd(&hist[(key >> shift) & 255u], 1u);
        }
        __syncthreads();
        if (tid == 0) {
            unsigned int cum = 0;
            int dsel = 0;
            for (int d = 255; d >= 0; --d) {
                const unsigned int c = hist[d];
                if (cum + c >= remaining) { dsel = d; break; }
                cum += c;
            }
            sh_digit = (unsigned int)dsel;
            sh_remaining = remaining - cum;   // rank within this digit's bucket
        }
        __syncthreads();
        prefix |= sh_digit << shift;
        pmask  |= 255u << shift;
        remaining = sh_remaining;
        __syncthreads();
    }
    // prefix == exact key of the k-th largest element.
    // remaining == how many elements equal to it are included (lowest index first).

    // Stable exclusive scan of per-thread equal-counts (consecutive f per thread).
    unsigned int myeq = 0;
    for (int i = 0; i < 16; ++i) myeq += (keys[tid * 16 + i] == prefix);
    tcnt[tid] = myeq;
    __syncthreads();
    if (tid == 0) {
        unsigned int run = 0;
        for (int t = 0; t < 256; ++t) {
            const unsigned int c = tcnt[t];
            tcnt[t] = run;
            run += c;
        }
    }
    __syncthreads();

    unsigned int rank = tcnt[tid];
    for (int i = 0; i < 16; ++i) {
        const int f = tid * 16 + i;
        const unsigned int key = keys[f];
        float m = 0.0f;
        if (key > prefix) {
            m = 1.0f;
        } else if (key == prefix) {
            m = (rank < remaining) ? 1.0f : 0.0f;
            rank++;
        }
        mask_out[((size_t)b * FF + f) * HH + h] = m;
    }
}

// ---------------------------------------------------------------------------
// K3: x_filtered = x * mask[b][f][d>>7], float4 vectorized grid-stride.
// ---------------------------------------------------------------------------
__global__ __launch_bounds__(256) void k_filter(const float* __restrict__ x,
                                                const float* __restrict__ mask,
                                                float* __restrict__ out) {
    const size_t total4 = (size_t)BB * FF * DD / 4;   // 8,388,608
    const size_t stride = (size_t)gridDim.x * blockDim.x;
    const float4* x4 = (const float4*)x;
    float4* o4 = (float4*)out;
    for (size_t i = (size_t)blockIdx.x * blockDim.x + threadIdx.x;
         i < total4; i += stride) {
        const size_t r = i >> 8;                        // row index b*F+f
        const unsigned int dpos4 = (unsigned int)i & 255u;
        const unsigned int h = dpos4 >> 5;              // 32 float4 per head
        const float mv = mask[r * HH + h];
        float4 v = x4[i];
        v.x *= mv; v.y *= mv; v.z *= mv; v.w *= mv;
        o4[i] = v;
    }
}

extern "C" void kernel_launch(void* const* d_in, const int* in_sizes, int n_in,
                              void* d_out, int out_size, void* d_ws, size_t ws_size,
                              hipStream_t stream) {
    const float* x  = (const float*)d_in[0];   // (B,F,D)
    const float* W  = (const float*)d_in[1];   // (D,H)
    const float* bi = (const float*)d_in[2];   // (H,)
    const float* so = (const float*)d_in[3];   // (H,)

    float* out_x    = (float*)d_out;                         // B*F*D
    float* out_mask = (float*)d_out + (size_t)BB * FF * DD;  // B*F*H
    float* scores   = (float*)d_ws;                          // B*F*H floats (1 MB)

    k_scores<<<1024, 256, 0, stream>>>(x, W, bi, scores);
    k_topk<<<BB * HH, 256, 0, stream>>>(scores, so, out_mask);
    k_filter<<<8192, 256, 0, stream>>>(x, out_mask, out_x);
}

// Round 3
// 302.425 us; speedup vs baseline: 1.3178x; 1.3178x over previous
//
#include <hip/hip_runtime.h>
#include <math.h>

#define BB 8
#define FF 4096
#define DD 1024
#define HH 8
#define BF (BB * FF)   // 32768 rows

// ---------------------------------------------------------------------------
// K1: scoresT[h*BF + r] = sum_d |x[r][d]| * W[d][h] + b[h], f64 accumulation.
// One wave per 4 rows. Lane owns d = (lane+64j)*4+c (c=0..3, j=0..3); W slice
// reloaded per j (L1/L2-hot, amortized over 4 rows). Reduction: fold heads
// across lane bits 5,4,3 (8+4+2 b32 shuffles) then 3-step 8-lane reduce.
// ---------------------------------------------------------------------------
__global__ __launch_bounds__(256) void k_scores(const float* __restrict__ x,
                                                const float* __restrict__ W,
                                                const float* __restrict__ b,
                                                float* __restrict__ scoresT) {
    const int lane = threadIdx.x & 63;
    const int wid  = blockIdx.x * 4 + (threadIdx.x >> 6);
    const int r0   = wid * 4;                       // 4 rows per wave

    double acc[4][8];
#pragma unroll
    for (int r = 0; r < 4; ++r)
#pragma unroll
        for (int h = 0; h < 8; ++h) acc[r][h] = 0.0;

#pragma unroll
    for (int j = 0; j < 4; ++j) {
        const int dbase = (lane + 64 * j) * 4;
        float wv[4][8];
#pragma unroll
        for (int c = 0; c < 4; ++c) {
            const float4* wp = (const float4*)(W + (size_t)(dbase + c) * HH);
            float4 w0 = wp[0], w1 = wp[1];
            wv[c][0] = w0.x; wv[c][1] = w0.y; wv[c][2] = w0.z; wv[c][3] = w0.w;
            wv[c][4] = w1.x; wv[c][5] = w1.y; wv[c][6] = w1.z; wv[c][7] = w1.w;
        }
#pragma unroll
        for (int r = 0; r < 4; ++r) {
            float4 v = ((const float4*)(x + (size_t)(r0 + r) * DD))[lane + 64 * j];
            const float m0 = fabsf(v.x), m1 = fabsf(v.y),
                        m2 = fabsf(v.z), m3 = fabsf(v.w);
#pragma unroll
            for (int h = 0; h < 8; ++h)
                acc[r][h] += (double)m0 * (double)wv[0][h]
                           + (double)m1 * (double)wv[1][h]
                           + (double)m2 * (double)wv[2][h]
                           + (double)m3 * (double)wv[3][h];
        }
    }

    const int b5 = (lane >> 5) & 1, b4 = (lane >> 4) & 1, b3 = (lane >> 3) & 1;
#pragma unroll
    for (int r = 0; r < 4; ++r) {
        // fold xor32: keep heads [b5*4, b5*4+4)
        double t[4];
#pragma unroll
        for (int i = 0; i < 4; ++i) {
            double send = b5 ? acc[r][i] : acc[r][4 + i];
            double recv = __shfl_xor(send, 32, 64);
            t[i] = (b5 ? acc[r][4 + i] : acc[r][i]) + recv;
        }
        // fold xor16: keep 2
        double u[2];
#pragma unroll
        for (int i = 0; i < 2; ++i) {
            double send = b4 ? t[i] : t[2 + i];
            double recv = __shfl_xor(send, 16, 64);
            u[i] = (b4 ? t[2 + i] : t[i]) + recv;
        }
        // fold xor8: keep 1 → head h = b5*4 + b4*2 + b3 = lane>>3 on lanes 8h
        double s;
        {
            double send = b3 ? u[0] : u[1];
            double recv = __shfl_xor(send, 8, 64);
            s = (b3 ? u[1] : u[0]) + recv;
        }
        s += __shfl_xor(s, 4, 64);
        s += __shfl_xor(s, 2, 64);
        s += __shfl_xor(s, 1, 64);
        if ((lane & 7) == 0) {
            const int h = lane >> 3;
            scoresT[(size_t)h * BF + (r0 + r)] = (float)(s + (double)b[h]);
        }
    }
}

// ---------------------------------------------------------------------------
// K2: per (b,h) exact top-k via 8-bit radix select; all scans parallel.
// Reads scoresT slice (coalesced), overwrites it in place with maskT.
// ---------------------------------------------------------------------------
__global__ __launch_bounds__(256) void k_topk(float* scoresT,
                                              const float* __restrict__ soff) {
    const int blk = blockIdx.x;      // b*H + h
    const int b   = blk >> 3;
    const int h   = blk & 7;
    const int tid = threadIdx.x;

    __shared__ unsigned int keys[FF];        // 16 KB
    __shared__ unsigned int hist[256];
    __shared__ unsigned int scan[256];
    __shared__ unsigned int sh_digit, sh_rem;

    // k per head — mirror the reference's float64 path.
    double o  = (double)soff[h];
    double sp = 1.0 / (1.0 + exp(-o)) * 0.3 + 0.15;
    int k = (int)((double)FF * sp);
    if (k < 1) k = 1;

    const size_t base = (size_t)h * BF + (size_t)b * FF;

    // Coalesced load -> order-preserving keys.
    for (int i = 0; i < 16; ++i) {
        const int f = i * 256 + tid;
        const unsigned int u = __float_as_uint(scoresT[base + f]);
        keys[f] = (u & 0x80000000u) ? ~u : (u | 0x80000000u);
    }
    __syncthreads();

    unsigned int remaining = (unsigned int)k;
    unsigned int prefix = 0, pmask = 0;
    for (int pass = 3; pass >= 0; --pass) {
        const int shift = pass * 8;
        hist[tid] = 0;
        __syncthreads();
        for (int i = 0; i < 16; ++i) {
            const unsigned int key = keys[i * 256 + tid];
            if ((key & pmask) == prefix)
                atomicAdd(&hist[(key >> shift) & 255u], 1u);
        }
        __syncthreads();
        // suffix inclusive scan: scan[d] = sum_{d'>=d} hist[d']
        scan[tid] = hist[tid];
        for (int off = 1; off < 256; off <<= 1) {
            __syncthreads();
            const unsigned int add = (tid + off < 256) ? scan[tid + off] : 0u;
            __syncthreads();
            scan[tid] += add;
        }
        __syncthreads();
        const unsigned int Sd    = scan[tid];
        const unsigned int Snext = (tid < 255) ? scan[tid + 1] : 0u;
        if (Sd >= remaining && Snext < remaining) {
            sh_digit = (unsigned int)tid;
            sh_rem   = remaining - Snext;
        }
        __syncthreads();
        prefix |= sh_digit << shift;
        pmask  |= 255u << shift;
        remaining = sh_rem;
        __syncthreads();
    }
    // prefix = key of k-th largest; remaining = #equal keys to keep (lowest f).

    // Stable rank of equal keys: thread owns consecutive f = tid*16..+16.
    unsigned int cnt = 0;
    for (int i = 0; i < 16; ++i) cnt += (keys[tid * 16 + i] == prefix);
    scan[tid] = cnt;
    for (int off = 1; off < 256; off <<= 1) {
        __syncthreads();
        const unsigned int add = (tid >= off) ? scan[tid - off] : 0u;
        __syncthreads();
        scan[tid] += add;
    }
    __syncthreads();
    unsigned int rank = scan[tid] - cnt;   // exclusive prefix

    // Overwrite scoresT slice with the mask (maskT layout), float4 stores.
    float mbuf[16];
    for (int i = 0; i < 16; ++i) {
        const unsigned int key = keys[tid * 16 + i];
        float m = 0.0f;
        if (key > prefix) {
            m = 1.0f;
        } else if (key == prefix) {
            m = (rank < remaining) ? 1.0f : 0.0f;
            rank++;
        }
        mbuf[i] = m;
    }
    float4* dst = (float4*)(scoresT + base + (size_t)tid * 16);
    for (int q = 0; q < 4; ++q)
        dst[q] = make_float4(mbuf[q * 4], mbuf[q * 4 + 1], mbuf[q * 4 + 2], mbuf[q * 4 + 3]);
}

// ---------------------------------------------------------------------------
// K3: out_x = x * maskT[h][r]; also emits out_mask in (B,F,H) layout.
// ---------------------------------------------------------------------------
__global__ __launch_bounds__(256) void k_filter(const float* __restrict__ x,
                                                const float* __restrict__ maskT,
                                                float* __restrict__ out_x,
                                                float* __restrict__ out_mask) {
    const size_t total4 = (size_t)BB * FF * DD / 4;   // 8,388,608
    const size_t stride = (size_t)gridDim.x * blockDim.x;
    const float4* x4 = (const float4*)x;
    float4* o4 = (float4*)out_x;
    for (size_t i = (size_t)blockIdx.x * blockDim.x + threadIdx.x;
         i < total4; i += stride) {
        const size_t r = i >> 8;                        // row b*F+f
        const unsigned int j = (unsigned int)i & 255u;
        const unsigned int h = j >> 5;                  // 32 float4 per head
        const float mv = maskT[(size_t)h * BF + r];
        float4 v = x4[i];
        v.x *= mv; v.y *= mv; v.z *= mv; v.w *= mv;
        o4[i] = v;
        if (j < 8)
            out_mask[r * HH + j] = maskT[(size_t)j * BF + r];
    }
}

extern "C" void kernel_launch(void* const* d_in, const int* in_sizes, int n_in,
                              void* d_out, int out_size, void* d_ws, size_t ws_size,
                              hipStream_t stream) {
    const float* x  = (const float*)d_in[0];   // (B,F,D)
    const float* W  = (const float*)d_in[1];   // (D,H)
    const float* bi = (const float*)d_in[2];   // (H,)
    const float* so = (const float*)d_in[3];   // (H,)

    float* out_x    = (float*)d_out;                         // B*F*D
    float* out_mask = (float*)d_out + (size_t)BB * FF * DD;  // B*F*H
    float* scoresT  = (float*)d_ws;                          // [H][BF] floats (1 MB)

    k_scores<<<2048, 256, 0, stream>>>(x, W, bi, scoresT);
    k_topk<<<BB * HH, 256, 0, stream>>>(scoresT, so);
    k_filter<<<8192, 256, 0, stream>>>(x, scoresT, out_x, out_mask);
}